// Round 4
// baseline (140.122 us; speedup 1.0000x reference)
//
#include <hip/hip_runtime.h>

// Problem constants (B=2, T=2048, D=1024, H=16, L=12, DH=64)
#define TT 2048
#define DD 1024
#define MTOT 4096   // B*T

typedef float f32x4  __attribute__((ext_vector_type(4)));
typedef float f32x16 __attribute__((ext_vector_type(16)));

__device__ __forceinline__ unsigned short f2bf(float f) {
  union { float f; unsigned u; } c; c.f = f;
  return (unsigned short)((c.u + 0x7fffu + ((c.u >> 16) & 1u)) >> 16);
}

__device__ __forceinline__ void mfma16(f32x4& d, f32x4 a, f32x4 b) {
  asm volatile("v_mfma_f32_16x16x32_bf16 %0, %1, %2, %0" : "+v"(d) : "v"(a), "v"(b));
}
__device__ __forceinline__ void mfma32(f32x16& d, f32x4 a, f32x4 b) {
  asm volatile("v_mfma_f32_32x32x16_bf16 %0, %1, %2, %0" : "+v"(d) : "v"(a), "v"(b));
}
__device__ __forceinline__ float cvtpk(float lo, float hi) {
  float r;
  asm("v_cvt_pk_bf16_f32 %0, %1, %2" : "=v"(r) : "v"(lo), "v"(hi));
  return r;
}
__device__ __forceinline__ void plswap(float& a, float& b) {
  asm volatile("v_permlane32_swap_b32 %0, %1" : "+v"(a), "+v"(b));
}
__device__ __forceinline__ void gld16(void* lds, const void* g) {
  __builtin_amdgcn_global_load_lds(
      (const __attribute__((address_space(1))) unsigned int*)g,
      (__attribute__((address_space(3))) unsigned int*)lds, 16, 0, 0);
}
__device__ __forceinline__ void mfma_fence() {
  asm volatile("s_nop 7\n\ts_nop 7\n\ts_nop 7");
}
__device__ __forceinline__ void snop1() { asm volatile("s_nop 1"); }

// ---------------- prep kernels ----------------

__global__ void cast_x_kernel(const float* __restrict__ x, unsigned short* __restrict__ xbf) {
  int i = blockIdx.x * 256 + threadIdx.x;
  float4 v = ((const float4*)x)[i];
  ushort4 o; o.x = f2bf(v.x); o.y = f2bf(v.y); o.z = f2bf(v.z); o.w = f2bf(v.w);
  ((ushort4*)xbf)[i] = o;
}

// Fused transpose: Wcat[4352][1024] bf16 = [Wq^T;Wk^T;Wv^T;Wl^T;pad;Wo^T]
__global__ void transpose_all(const float* __restrict__ Wq, const float* __restrict__ Wk,
                              const float* __restrict__ Wv, const float* __restrict__ Wl,
                              const float* __restrict__ Wo, unsigned short* __restrict__ Wcat) {
  __shared__ float tile[32][33];
  int n0 = blockIdx.x * 32, k0 = blockIdx.y * 32;
  int tx = threadIdx.x, ty = threadIdx.y;  // 32 x 8
  const float* src; int scol = 0, sN = 1024;
  if (n0 < 1024)      { src = Wq; scol = n0; }
  else if (n0 < 2048) { src = Wk; scol = n0 - 1024; }
  else if (n0 < 3072) { src = Wv; scol = n0 - 2048; }
  else if (n0 < 3264) { src = Wl; scol = n0 - 3072; sN = 192; }
  else if (n0 < 3328) { src = nullptr; }
  else                { src = Wo; scol = n0 - 3328; }
  if (src) {
#pragma unroll
    for (int i = 0; i < 4; ++i) tile[ty + i * 8][tx] = src[(k0 + ty + i * 8) * sN + scol + tx];
  }
  __syncthreads();
#pragma unroll
  for (int i = 0; i < 4; ++i)
    Wcat[(n0 + ty + i * 8) * 1024 + k0 + tx] = src ? f2bf(tile[tx][ty + i * 8]) : (unsigned short)0;
}

// ---------------- GEMM core: C = A[4096,1024] * Bt[*,1024]^T + bias ----------------
// Double-buffered LDS, one barrier per K-step (T3-minimum).
// MODE 0: fused QKVL epilogue; MODE 1: fp32 row-major out.
template <int MODE>
__device__ __forceinline__ void gemm_body(
    const unsigned short* __restrict__ A, const unsigned short* __restrict__ Bt,
    const float* __restrict__ b0p, const float* __restrict__ b1p,
    const float* __restrict__ b2p, const float* __restrict__ b3p,
    void* __restrict__ o0p, void* __restrict__ o1p, void* __restrict__ o2p, void* __restrict__ o3p) {
  __shared__ unsigned short As[2][128 * 64];
  __shared__ unsigned short Bs[2][128 * 64];
  const int tid = threadIdx.x;
  const int wid = tid >> 6, lane = tid & 63, l16 = lane & 15, g = lane >> 4;
  const int wm = wid >> 1, wn = wid & 1;
  const int m0 = blockIdx.y * 128, n0 = blockIdx.x * 128;
  const int rowlane = lane >> 3;
  const int swz = (lane & 7) ^ rowlane;

  f32x4 acc[4][4] = {};

  auto stage = [&](int kb, int buf) {
#pragma unroll
    for (int i = 0; i < 4; ++i) {
      int c = wid * 4 + i;
      int row = c * 8 + rowlane;
      gld16((char*)&As[buf][0] + c * 1024, A + (size_t)(m0 + row) * 1024 + kb * 64 + swz * 8);
      gld16((char*)&Bs[buf][0] + c * 1024, Bt + (size_t)(n0 + row) * 1024 + kb * 64 + swz * 8);
    }
  };

  stage(0, 0);
  int cur = 0;
  for (int kb = 0; kb < 16; ++kb) {
    __syncthreads();                       // buf[cur] fully staged
    if (kb < 15) stage(kb + 1, cur ^ 1);   // issue next-tile loads first
#pragma unroll
    for (int kk = 0; kk < 2; ++kk) {
      f32x4 a[4], b[4];
#pragma unroll
      for (int f = 0; f < 4; ++f) {
        int ra = wm * 64 + f * 16 + l16;
        a[f] = *(const f32x4*)((const char*)&As[cur][0] + ra * 128 + (((kk * 4 + g) ^ (ra & 7)) << 4));
        int rb = wn * 64 + f * 16 + l16;
        b[f] = *(const f32x4*)((const char*)&Bs[cur][0] + rb * 128 + (((kk * 4 + g) ^ (rb & 7)) << 4));
      }
#pragma unroll
      for (int mf = 0; mf < 4; ++mf)
#pragma unroll
        for (int nf = 0; nf < 4; ++nf) mfma16(acc[mf][nf], a[mf], b[nf]);
    }
    cur ^= 1;
  }
  mfma_fence();

  // epilogue: m = m0+wm*64+mf*16+g*4+r ; n = n0+wn*64+nf*16+l16
#pragma unroll
  for (int nf = 0; nf < 4; ++nf) {
    int n = n0 + wn * 64 + nf * 16 + l16;
#pragma unroll
    for (int mf = 0; mf < 4; ++mf) {
      int m = m0 + wm * 64 + mf * 16 + g * 4;
      int bb = m >> 11, t = m & 2047;
      f32x4 v = acc[mf][nf];
      if (MODE == 1) {
        float bv = b0p[n];
        float* dst = (float*)o0p + ((size_t)m << 10) + n;
#pragma unroll
        for (int r = 0; r < 4; ++r) dst[(size_t)r << 10] = v[r] + bv;
      } else {
        int seg = n >> 10;                  // 0=Q 1=K 2=V 3=lam (uniform per block)
        int np = n & 1023;
        if (seg <= 1) {
          float bv = seg == 0 ? b0p[np] : b1p[np];
          unsigned short* dst = (unsigned short*)(seg == 0 ? o0p : o1p) +
              ((size_t)((bb << 4) + (np >> 6)) * TT + t) * 64 + (np & 63);
#pragma unroll
          for (int r = 0; r < 4; ++r) dst[r * 64] = f2bf(v[r] + bv);
        } else if (seg == 2) {
          float bv = b2p[np];
          ushort4 pk;
          pk.x = f2bf(v[0] + bv); pk.y = f2bf(v[1] + bv);
          pk.z = f2bf(v[2] + bv); pk.w = f2bf(v[3] + bv);
          *(ushort4*)((unsigned short*)o2p +
              ((size_t)((bb << 4) + (np >> 6)) * 64 + (np & 63)) * TT + t) = pk;
        } else if (np < 192) {
          float bv = b3p[np];
          int h = np / 12, l = np - h * 12;
          float* dst = (float*)o3p + ((size_t)((bb << 4) + h) * TT + t) * 12 + l;
#pragma unroll
          for (int r = 0; r < 4; ++r) {
            float s = v[r] + bv;
            dst[r * 12] = fmaxf(s, 0.f) + log1pf(expf(-fabsf(s)));
          }
        }
      }
    }
  }
}

__global__ __launch_bounds__(256, 2) void gemm_qkvl(
    const unsigned short* __restrict__ A, const unsigned short* __restrict__ Bt,
    const float* b0, const float* b1, const float* b2, const float* b3,
    void* o0, void* o1, void* o2, void* o3) {
  gemm_body<0>(A, Bt, b0, b1, b2, b3, o0, o1, o2, o3);
}

__global__ __launch_bounds__(256, 2) void gemm_out(
    const unsigned short* __restrict__ A, const unsigned short* __restrict__ Bt,
    const float* b0, void* o0) {
  gemm_body<1>(A, Bt, b0, nullptr, nullptr, nullptr, o0, nullptr, nullptr, nullptr);
}

// ---------------- Fenwick-masked attention v3: dual q-tile ----------------
// O = (M o Q K^T) V per (b,h); M[tq,ti] = lam[tq][31-clz((tq+1)^ti)], ti<=tq.
// Block (bh, j) handles q-tiles jA=j and jB=15-j (shared K/V staging, balanced:
// 17 compute-units/block). 256 blocks, 4 waves, KVBLK=128, dbuf, P in regs.
__global__ __launch_bounds__(256, 1) void attn_fenwick3(
    const unsigned short* __restrict__ Qp, const unsigned short* __restrict__ Kp,
    const unsigned short* __restrict__ Vt, const float* __restrict__ lamp,
    unsigned short* __restrict__ Y) {
  __shared__ unsigned short Ks[2][64 * 128];  // [r=key&63][h*64+d], 16-chunk XOR swz
  __shared__ unsigned short Vs[2][64 * 128];  // [d][key], 16-chunk XOR swz
  __shared__ float lamlA[12 * 128];           // [lvl][q] (bank = q, conflict-free)
  __shared__ float lamlB[12 * 128];

  const int tid = threadIdx.x;
  const int w = tid >> 6, lane = tid & 63;
  const int q5 = lane & 31, hi = lane >> 5;

  const int bx = blockIdx.x;
  const int bh = bx >> 3, j = bx & 7;
  const int jA = j, jB = 15 - j;

  const int qloc = w * 32 + q5;
  const int tqA = jA * 128 + qloc;
  const int tqB = jB * 128 + qloc;

  {
    const float* srcA = lamp + ((size_t)bh * TT + jA * 128) * 12;
    const float* srcB = lamp + ((size_t)bh * TT + jB * 128) * 12;
    for (int i = tid; i < 1536; i += 256) {
      int q = i / 12, l = i - q * 12;
      lamlA[l * 128 + q] = srcA[i];
      lamlB[l * 128 + q] = srcB[i];
    }
  }

  // Q B-frags (4 k-slices of 16): lane holds Q[tq][ks*16 + hi*8 .. +8)
  f32x4 qfA[4], qfB[4];
  {
    const unsigned short* QrA = Qp + ((size_t)bh * TT + tqA) * 64;
    const unsigned short* QrB = Qp + ((size_t)bh * TT + tqB) * 64;
#pragma unroll
    for (int ks = 0; ks < 4; ++ks) {
      qfA[ks] = *(const f32x4*)(QrA + ks * 16 + hi * 8);
      qfB[ks] = *(const f32x4*)(QrB + ks * 16 + hi * 8);
    }
  }

  f32x16 oA0 = (f32x16)0.f, oA1 = (f32x16)0.f;
  f32x16 oB0 = (f32x16)0.f, oB1 = (f32x16)0.f;

  const unsigned short* Kbh = Kp + (size_t)bh * (TT * 64);
  const unsigned short* Vbh = Vt + (size_t)bh * (64 * TT);

  auto stage = [&](int kb, int buf) {
#pragma unroll
    for (int i = 0; i < 4; ++i) {
      int ch = w * 4 + i;
      int o = ch * 1024 + lane * 16;
      int r = o >> 8;                // dest row
      int cp = (o >> 4) & 15;        // swizzled chunk-in-row
      int c = cp ^ (r & 15);
      gld16((char*)&Ks[buf][0] + ch * 1024,
            Kbh + (size_t)(kb * 128 + (c >> 3) * 64 + r) * 64 + (c & 7) * 8);
      gld16((char*)&Vs[buf][0] + ch * 1024,
            Vbh + (size_t)r * TT + kb * 128 + c * 8);
    }
  };

  auto do_tile = [&](int kb, int cur, int tqg, const float* laml, const f32x4* qf,
                     f32x16& o0, f32x16& o1, bool diag) {
    const char* Kbase = (const char*)&Ks[cur][0];
    const char* Vbase = (const char*)&Vs[cur][0];
    const int ntiles = diag ? (w + 1) : 4;

    // S^T = K * Q^T per 32-key tile: lane owns col q=q5, rows=keys
    f32x16 s[4];
#pragma unroll
    for (int t = 0; t < 4; ++t) {
      if (t >= ntiles) continue;
      s[t] = (f32x16)0.f;
      int r = (t & 1) * 32 + q5;
      int h = t >> 1;
#pragma unroll
      for (int ks = 0; ks < 4; ++ks) {
        int c = h * 8 + ks * 2 + hi;
        f32x4 kf = *(const f32x4*)(Kbase + r * 256 + ((c ^ (r & 15)) << 4));
        mfma32(s[t], kf, qf[ks]);
      }
    }
    mfma_fence();

#pragma unroll
    for (int t = 0; t < 4; ++t) {
      if (t >= ntiles) continue;
      int key64 = (kb << 1) + (t >> 1);
      float pkv[8];
      if (!diag || ((t >> 1) != (w >> 1))) {
        int lvl = 37 - __clz(((tqg + 1) >> 6) ^ key64);
        float wv = laml[lvl * 128 + qloc];
#pragma unroll
        for (int i = 0; i < 8; ++i)
          pkv[i] = cvtpk(s[t][2 * i] * wv, s[t][2 * i + 1] * wv);
      } else {
        // per-element level (+causal) — same 64-block
#pragma unroll
        for (int i = 0; i < 8; ++i) {
          float pe[2];
#pragma unroll
          for (int e = 0; e < 2; ++e) {
            int reg = 2 * i + e;
            int tig = kb * 128 + t * 32 + (reg & 3) + 8 * (reg >> 2) + 4 * hi;
            float pv = 0.f;
            if (tig <= tqg) {
              int lvl = 31 - __clz((tqg + 1) ^ tig);
              pv = s[t][reg] * laml[lvl * 128 + qloc];
            }
            pe[e] = pv;
          }
          pkv[i] = cvtpk(pe[0], pe[1]);
        }
      }
      // redistribute: pkv[0..3] = B-frag(kstep 2t), pkv[4..7] = B-frag(2t+1)
      plswap(pkv[0], pkv[2]);
      plswap(pkv[1], pkv[3]);
      plswap(pkv[4], pkv[6]);
      plswap(pkv[5], pkv[7]);
      f32x4 f0 = {pkv[0], pkv[1], pkv[2], pkv[3]};
      f32x4 f1 = {pkv[4], pkv[5], pkv[6], pkv[7]};
      snop1();
      int s0c = 4 * t + hi;          // Vs chunk = 2*kstep + hi
#pragma unroll
      for (int dg = 0; dg < 2; ++dg) {
        int row = dg * 32 + q5;
        f32x4 v0 = *(const f32x4*)(Vbase + row * 256 + ((s0c ^ (row & 15)) << 4));
        f32x4 v1 = *(const f32x4*)(Vbase + row * 256 + (((s0c + 2) ^ (row & 15)) << 4));
        if (dg) { mfma32(o1, v0, f0); mfma32(o1, v1, f1); }
        else    { mfma32(o0, v0, f0); mfma32(o0, v1, f1); }
      }
    }
  };

  stage(0, 0);
  int cur = 0;

  for (int kb = 0; kb <= jB; ++kb) {
    __syncthreads();                 // buf[cur] staged
    if (kb < jB) stage(kb + 1, cur ^ 1);
    do_tile(kb, cur, tqB, lamlB, qfB, oB0, oB1, kb == jB);
    if (kb <= jA) do_tile(kb, cur, tqA, lamlA, qfA, oA0, oA1, kb == jA);
    cur ^= 1;
  }
  mfma_fence();

  // store: O^T col=q (lane), rows d = dg*32 + 8*rq + 4*hi + (0..3)
  int b = bh >> 4, h = bh & 15;
  unsigned short* yA = Y + ((size_t)(b * TT + tqA)) * DD + h * 64;
  unsigned short* yB = Y + ((size_t)(b * TT + tqB)) * DD + h * 64;
#pragma unroll
  for (int dg = 0; dg < 2; ++dg) {
    f32x16 oa = dg ? oA1 : oA0;
    f32x16 ob = dg ? oB1 : oB0;
#pragma unroll
    for (int rq = 0; rq < 4; ++rq) {
      ushort4 pa, pb;
      pa.x = f2bf(oa[4 * rq + 0]); pa.y = f2bf(oa[4 * rq + 1]);
      pa.z = f2bf(oa[4 * rq + 2]); pa.w = f2bf(oa[4 * rq + 3]);
      pb.x = f2bf(ob[4 * rq + 0]); pb.y = f2bf(ob[4 * rq + 1]);
      pb.z = f2bf(ob[4 * rq + 2]); pb.w = f2bf(ob[4 * rq + 3]);
      *(ushort4*)(yA + dg * 32 + 8 * rq + 4 * hi) = pa;
      *(ushort4*)(yB + dg * 32 + 8 * rq + 4 * hi) = pb;
    }
  }
}

// ---------------- host ----------------

extern "C" void kernel_launch(void* const* d_in, const int* in_sizes, int n_in,
                              void* d_out, int out_size, void* d_ws, size_t ws_size,
                              hipStream_t stream) {
  const float* x  = (const float*)d_in[0];
  const float* Wq = (const float*)d_in[1];
  const float* bq = (const float*)d_in[2];
  const float* Wk = (const float*)d_in[3];
  const float* bk = (const float*)d_in[4];
  const float* Wv = (const float*)d_in[5];
  const float* bv = (const float*)d_in[6];
  const float* Wl = (const float*)d_in[7];
  const float* bl = (const float*)d_in[8];
  const float* Wo = (const float*)d_in[9];
  const float* bo = (const float*)d_in[10];

  char* ws = (char*)d_ws;
  size_t off = 0;
  auto alloc = [&](size_t bytes) { char* p = ws + off; off += bytes; return p; };

  unsigned short* xbf  = (unsigned short*)alloc((size_t)MTOT * DD * 2);      // 8 MB
  unsigned short* Wcat = (unsigned short*)alloc((size_t)4352 * DD * 2);      // 8.9 MB
  unsigned short* Qp   = (unsigned short*)alloc((size_t)MTOT * DD * 2);      // [B,H,T,64]
  unsigned short* Kp   = (unsigned short*)alloc((size_t)MTOT * DD * 2);
  unsigned short* Vtb  = (unsigned short*)alloc((size_t)MTOT * DD * 2);      // [B,H,64,T]
  float*          lamp = (float*)alloc((size_t)32 * TT * 12 * 4);            // [B,H,T,12]
  unsigned short* Y    = (unsigned short*)alloc((size_t)MTOT * DD * 2);
  (void)ws_size; (void)off; (void)in_sizes; (void)n_in; (void)out_size;

  cast_x_kernel<<<MTOT * DD / 4 / 256, 256, 0, stream>>>(x, xbf);
  transpose_all<<<dim3(136, 32), dim3(32, 8), 0, stream>>>(Wq, Wk, Wv, Wl, Wo, Wcat);

  gemm_qkvl<<<dim3(26, 32), 256, 0, stream>>>(
      xbf, Wcat, bq, bk, bv, bl, Qp, Kp, Vtb, lamp);

  attn_fenwick3<<<dim3(256), 256, 0, stream>>>(Qp, Kp, Vtb, lamp, Y);

  gemm_out<<<dim3(8, 32), 256, 0, stream>>>(
      Y, Wcat + (size_t)3328 * 1024, bo, (float*)d_out);
}

// Round 8
// 130.988 us; speedup vs baseline: 1.0697x; 1.0697x over previous
//
#include <hip/hip_runtime.h>

// Problem constants (B=2, T=2048, D=1024, H=16, L=12, DH=64)
#define TT 2048
#define DD 1024
#define MTOT 4096   // B*T

typedef float f32x4  __attribute__((ext_vector_type(4)));
typedef float f32x16 __attribute__((ext_vector_type(16)));

__device__ __forceinline__ unsigned short f2bf(float f) {
  union { float f; unsigned u; } c; c.f = f;
  return (unsigned short)((c.u + 0x7fffu + ((c.u >> 16) & 1u)) >> 16);
}

__device__ __forceinline__ void mfma16(f32x4& d, f32x4 a, f32x4 b) {
  asm volatile("v_mfma_f32_16x16x32_bf16 %0, %1, %2, %0" : "+v"(d) : "v"(a), "v"(b));
}
__device__ __forceinline__ void mfma32(f32x16& d, f32x4 a, f32x4 b) {
  asm volatile("v_mfma_f32_32x32x16_bf16 %0, %1, %2, %0" : "+v"(d) : "v"(a), "v"(b));
}
__device__ __forceinline__ float cvtpk(float lo, float hi) {
  float r;
  asm("v_cvt_pk_bf16_f32 %0, %1, %2" : "=v"(r) : "v"(lo), "v"(hi));
  return r;
}
__device__ __forceinline__ void plswap(float& a, float& b) {
  asm volatile("v_permlane32_swap_b32 %0, %1" : "+v"(a), "+v"(b));
}
__device__ __forceinline__ void gld16(void* lds, const void* g) {
  __builtin_amdgcn_global_load_lds(
      (const __attribute__((address_space(1))) unsigned int*)g,
      (__attribute__((address_space(3))) unsigned int*)lds, 16, 0, 0);
}
__device__ __forceinline__ void mfma_fence() {
  asm volatile("s_nop 7\n\ts_nop 7\n\ts_nop 7");
}
__device__ __forceinline__ void snop1() { asm volatile("s_nop 1"); }

// ---------------- prep kernels ----------------

__global__ void cast_x_kernel(const float* __restrict__ x, unsigned short* __restrict__ xbf) {
  int i = blockIdx.x * 256 + threadIdx.x;
  float4 v = ((const float4*)x)[i];
  ushort4 o; o.x = f2bf(v.x); o.y = f2bf(v.y); o.z = f2bf(v.z); o.w = f2bf(v.w);
  ((ushort4*)xbf)[i] = o;
}

// Fused transpose: Wcat[4352][1024] bf16 = [Wq^T;Wk^T;Wv^T;Wl^T;pad;Wo^T]
__global__ void transpose_all(const float* __restrict__ Wq, const float* __restrict__ Wk,
                              const float* __restrict__ Wv, const float* __restrict__ Wl,
                              const float* __restrict__ Wo, unsigned short* __restrict__ Wcat) {
  __shared__ float tile[32][33];
  int n0 = blockIdx.x * 32, k0 = blockIdx.y * 32;
  int tx = threadIdx.x, ty = threadIdx.y;  // 32 x 8
  const float* src; int scol = 0, sN = 1024;
  if (n0 < 1024)      { src = Wq; scol = n0; }
  else if (n0 < 2048) { src = Wk; scol = n0 - 1024; }
  else if (n0 < 3072) { src = Wv; scol = n0 - 2048; }
  else if (n0 < 3264) { src = Wl; scol = n0 - 3072; sN = 192; }
  else if (n0 < 3328) { src = nullptr; }
  else                { src = Wo; scol = n0 - 3328; }
  if (src) {
#pragma unroll
    for (int i = 0; i < 4; ++i) tile[ty + i * 8][tx] = src[(k0 + ty + i * 8) * sN + scol + tx];
  }
  __syncthreads();
#pragma unroll
  for (int i = 0; i < 4; ++i)
    Wcat[(n0 + ty + i * 8) * 1024 + k0 + tx] = src ? f2bf(tile[tx][ty + i * 8]) : (unsigned short)0;
}

// ---------------- GEMM: C = A[4096,1024] * Bt[N,1024]^T + bias ----------------
// EXACT R2/R3-proven template body. Only the blockIdx -> (bx,by) mapping is
// new: SWZ=0 QKVL 832-block 2D XCD chunking (13x x 8y per XCD);
//      SWZ=1 out  512-block per-XCD by-slab.
// MODE 0: fused QKVL epilogue; MODE 1: fp32 row-major out.
template <int BM, int MODE, int SWZ>
__global__ __launch_bounds__(256, 2) void gemm2(
    const unsigned short* __restrict__ A, const unsigned short* __restrict__ Bt,
    const float* __restrict__ b0p, const float* __restrict__ b1p,
    const float* __restrict__ b2p, const float* __restrict__ b3p,
    void* __restrict__ o0p, void* __restrict__ o1p, void* __restrict__ o2p, void* __restrict__ o3p) {
  constexpr int MF = BM / 32;                 // m-frags per wave (wave = BM/2 rows)
  __shared__ unsigned short As[BM * 64];
  __shared__ unsigned short Bs[128 * 64];
  const int tid = threadIdx.x;
  const int wid = tid >> 6, lane = tid & 63, l16 = lane & 15, g = lane >> 4;
  const int wm = wid >> 1, wn = wid & 1;

  // XCD-locality block swizzle (bijective; bodies below unchanged)
  int bx, by;
  {
    int bid = blockIdx.x;
    int xcd = bid & 7, idx = bid >> 3;
    if (SWZ == 0) {              // 832 = 8 * (13x * 8y)
      int lx = idx % 13, ly = idx / 13;
      bx = (xcd & 1) * 13 + lx;
      by = (xcd >> 1) * 8 + ly;
    } else {                     // 512 = 8 * (8x * 8y-slab)
      by = xcd * 8 + (idx >> 3);
      bx = idx & 7;
    }
  }
  const int m0 = by * BM, n0 = bx * 128;
  const int rowlane = lane >> 3;
  const int swz = (lane & 7) ^ rowlane;

  f32x4 acc[MF][4] = {};

  for (int kb = 0; kb < 16; ++kb) {
    __syncthreads();
#pragma unroll
    for (int i = 0; i < MF; ++i) {           // A chunks: BM/8 total
      int c = wid * MF + i;
      int row = c * 8 + rowlane;
      gld16((char*)As + c * 1024, A + (size_t)(m0 + row) * 1024 + kb * 64 + swz * 8);
    }
#pragma unroll
    for (int i = 0; i < 4; ++i) {            // B chunks: 16 total
      int c = wid * 4 + i;
      int row = c * 8 + rowlane;
      gld16((char*)Bs + c * 1024, Bt + (size_t)(n0 + row) * 1024 + kb * 64 + swz * 8);
    }
    __syncthreads();
#pragma unroll
    for (int kk = 0; kk < 2; ++kk) {
      f32x4 a[MF], b[4];
#pragma unroll
      for (int f = 0; f < MF; ++f) {
        int ra = wm * (BM / 2) + f * 16 + l16;
        a[f] = *(const f32x4*)((const char*)As + ra * 128 + (((kk * 4 + g) ^ (ra & 7)) << 4));
      }
#pragma unroll
      for (int f = 0; f < 4; ++f) {
        int rb = wn * 64 + f * 16 + l16;
        b[f] = *(const f32x4*)((const char*)Bs + rb * 128 + (((kk * 4 + g) ^ (rb & 7)) << 4));
      }
#pragma unroll
      for (int mf = 0; mf < MF; ++mf)
#pragma unroll
        for (int nf = 0; nf < 4; ++nf) mfma16(acc[mf][nf], a[mf], b[nf]);
    }
  }
  mfma_fence();

  // epilogue: m = m0+wm*(BM/2)+mf*16+g*4+r ; n = n0+wn*64+nf*16+l16
#pragma unroll
  for (int nf = 0; nf < 4; ++nf) {
    int n = n0 + wn * 64 + nf * 16 + l16;
#pragma unroll
    for (int mf = 0; mf < MF; ++mf) {
      int m = m0 + wm * (BM / 2) + mf * 16 + g * 4;
      int bb = m >> 11, t = m & 2047;
      f32x4 v = acc[mf][nf];
      if (MODE == 1) {
        float bv = b0p[n];
        float* dst = (float*)o0p + ((size_t)m << 10) + n;
#pragma unroll
        for (int r = 0; r < 4; ++r) dst[(size_t)r << 10] = v[r] + bv;
      } else {
        int seg = n >> 10;                    // 0=Q 1=K 2=V 3=lam (uniform per block)
        int np = n & 1023;
        if (seg <= 1) {
          float bv = seg == 0 ? b0p[np] : b1p[np];
          unsigned short* dst = (unsigned short*)(seg == 0 ? o0p : o1p) +
              ((size_t)((bb << 4) + (np >> 6)) * TT + t) * 64 + (np & 63);
#pragma unroll
          for (int r = 0; r < 4; ++r) dst[r * 64] = f2bf(v[r] + bv);
        } else if (seg == 2) {
          float bv = b2p[np];
          ushort4 pk;
          pk.x = f2bf(v[0] + bv); pk.y = f2bf(v[1] + bv);
          pk.z = f2bf(v[2] + bv); pk.w = f2bf(v[3] + bv);
          *(ushort4*)((unsigned short*)o2p +
              ((size_t)((bb << 4) + (np >> 6)) * 64 + (np & 63)) * TT + t) = pk;
        } else if (np < 192) {
          float bv = b3p[np];
          int h = np / 12, l = np - h * 12;
          float* dst = (float*)o3p + ((size_t)((bb << 4) + h) * TT + t) * 12 + l;
#pragma unroll
          for (int r = 0; r < 4; ++r) {
            float s = v[r] + bv;
            dst[r * 12] = fmaxf(s, 0.f) + log1pf(expf(-fabsf(s)));
          }
        }
      }
    }
  }
}

// ---------------- Fenwick-masked attention v2 (R2-proven body) ----------------
// Only the blockIdx -> (bh,jq) mapping is new: all 16 q-tiles of a (b,h)
// share an XCD (bx&7 = bh>>2); CU pairing (bid, bid+256) -> jq + (15-jq) = 17
// units, constant, preserved.
__global__ __launch_bounds__(256, 2) void attn_fenwick2(
    const unsigned short* __restrict__ Qp, const unsigned short* __restrict__ Kp,
    const unsigned short* __restrict__ Vt, const float* __restrict__ lamp,
    unsigned short* __restrict__ Y) {
  __shared__ unsigned short Ks[2][64 * 128];  // [r=key&63][h*64+d], 16-chunk XOR swz
  __shared__ unsigned short Vs[2][64 * 128];  // [d][key], 16-chunk XOR swz
  __shared__ float laml[12 * 128];            // [lvl][q] -> bank = q (conflict-free)

  const int tid = threadIdx.x;
  const int w = tid >> 6, lane = tid & 63;
  const int q5 = lane & 31, hi = lane >> 5;

  // XCD-local + balanced mapping (bijective over [0,512))
  int bx = blockIdx.x;
  int lo = bx & 255;
  int bh = (lo & 7) * 4 + ((lo >> 3) & 3);
  int j0 = lo >> 5;
  int jq = (bx < 256) ? j0 : 15 - j0;

  const int qloc = w * 32 + q5;
  const int tqg = jq * 128 + qloc;

  {
    const float* src = lamp + ((size_t)bh * TT + jq * 128) * 12;
    for (int i = tid; i < 1536; i += 256) {
      int q = i / 12, l = i - q * 12;
      laml[l * 128 + q] = src[i];
    }
  }

  // Q B-frags (4 k-slices of 16): lane holds Q[tq][ks*16 + hi*8 .. +8)
  f32x4 qf[4];
  {
    const unsigned short* Qrow = Qp + ((size_t)bh * TT + tqg) * 64;
#pragma unroll
    for (int ks = 0; ks < 4; ++ks) qf[ks] = *(const f32x4*)(Qrow + ks * 16 + hi * 8);
  }

  f32x16 o0 = (f32x16)0.f, o1 = (f32x16)0.f;

  const unsigned short* Kbh = Kp + (size_t)bh * (TT * 64);
  const unsigned short* Vbh = Vt + (size_t)bh * (64 * TT);

  auto stage = [&](int kb, int buf) {
#pragma unroll
    for (int i = 0; i < 4; ++i) {
      int ch = w * 4 + i;
      int o = ch * 1024 + lane * 16;
      int r = o >> 8;                // dest row
      int cp = (o >> 4) & 15;        // swizzled chunk-in-row
      int c = cp ^ (r & 15);
      gld16((char*)&Ks[buf][0] + ch * 1024,
            Kbh + (size_t)(kb * 128 + (c >> 3) * 64 + r) * 64 + (c & 7) * 8);
      gld16((char*)&Vs[buf][0] + ch * 1024,
            Vbh + (size_t)r * TT + kb * 128 + c * 8);
    }
  };

  stage(0, 0);
  int cur = 0;

  for (int kb = 0; kb <= jq; ++kb) {
    __syncthreads();                 // drains vmcnt: buf[cur] staged; joins waves
    if (kb < jq) stage(kb + 1, cur ^ 1);
    const char* Kbase = (const char*)&Ks[cur][0];
    const char* Vbase = (const char*)&Vs[cur][0];
    const bool diag = (kb == jq);
    const int ntiles = diag ? (w + 1) : 4;

    // S^T = K * Q^T per 32-key tile: lane owns col q=q5, rows=keys
    f32x16 s[4];
#pragma unroll
    for (int t = 0; t < 4; ++t) {
      if (t >= ntiles) continue;
      s[t] = (f32x16)0.f;
      int r = (t & 1) * 32 + q5;
      int h = t >> 1;
#pragma unroll
      for (int ks = 0; ks < 4; ++ks) {
        int c = h * 8 + ks * 2 + hi;
        f32x4 kf = *(const f32x4*)(Kbase + r * 256 + ((c ^ (r & 15)) << 4));
        mfma32(s[t], kf, qf[ks]);
      }
    }
    mfma_fence();

#pragma unroll
    for (int t = 0; t < 4; ++t) {
      if (t >= ntiles) continue;
      int key64 = (kb << 1) + (t >> 1);
      float pkv[8];
      if (!diag || ((t >> 1) != (w >> 1))) {
        int lvl = 37 - __clz(((tqg + 1) >> 6) ^ key64);
        float wv = laml[lvl * 128 + qloc];
#pragma unroll
        for (int i = 0; i < 8; ++i)
          pkv[i] = cvtpk(s[t][2 * i] * wv, s[t][2 * i + 1] * wv);
      } else {
        // per-element level (+causal) — same 64-block
#pragma unroll
        for (int i = 0; i < 8; ++i) {
          float pe[2];
#pragma unroll
          for (int e = 0; e < 2; ++e) {
            int reg = 2 * i + e;
            int tig = kb * 128 + t * 32 + (reg & 3) + 8 * (reg >> 2) + 4 * hi;
            float pv = 0.f;
            if (tig <= tqg) {
              int lvl = 31 - __clz((tqg + 1) ^ tig);
              pv = s[t][reg] * laml[lvl * 128 + qloc];
            }
            pe[e] = pv;
          }
          pkv[i] = cvtpk(pe[0], pe[1]);
        }
      }
      // redistribute: pkv[0..3] = B-frag(kstep 2t), pkv[4..7] = B-frag(2t+1)
      plswap(pkv[0], pkv[2]);
      plswap(pkv[1], pkv[3]);
      plswap(pkv[4], pkv[6]);
      plswap(pkv[5], pkv[7]);
      f32x4 f0 = {pkv[0], pkv[1], pkv[2], pkv[3]};
      f32x4 f1 = {pkv[4], pkv[5], pkv[6], pkv[7]};
      snop1();
      int s0c = 4 * t + hi;          // Vs chunk = 2*kstep + hi
#pragma unroll
      for (int dg = 0; dg < 2; ++dg) {
        int row = dg * 32 + q5;
        f32x4 v0 = *(const f32x4*)(Vbase + row * 256 + ((s0c ^ (row & 15)) << 4));
        f32x4 v1 = *(const f32x4*)(Vbase + row * 256 + (((s0c + 2) ^ (row & 15)) << 4));
        if (dg) { mfma32(o1, v0, f0); mfma32(o1, v1, f1); }
        else    { mfma32(o0, v0, f0); mfma32(o0, v1, f1); }
      }
    }
    cur ^= 1;
  }
  mfma_fence();

  // store: O^T col=q (lane), rows d = dg*32 + 8*rq + 4*hi + (0..3)
  int b = bh >> 4, h = bh & 15;
  unsigned short* yrow = Y + ((size_t)(b * TT + tqg)) * DD + h * 64;
#pragma unroll
  for (int dg = 0; dg < 2; ++dg) {
    f32x16 o = dg ? o1 : o0;
#pragma unroll
    for (int rq = 0; rq < 4; ++rq) {
      ushort4 pk;
      pk.x = f2bf(o[4 * rq + 0]); pk.y = f2bf(o[4 * rq + 1]);
      pk.z = f2bf(o[4 * rq + 2]); pk.w = f2bf(o[4 * rq + 3]);
      *(ushort4*)(yrow + dg * 32 + 8 * rq + 4 * hi) = pk;
    }
  }
}

// ---------------- host ----------------

extern "C" void kernel_launch(void* const* d_in, const int* in_sizes, int n_in,
                              void* d_out, int out_size, void* d_ws, size_t ws_size,
                              hipStream_t stream) {
  const float* x  = (const float*)d_in[0];
  const float* Wq = (const float*)d_in[1];
  const float* bq = (const float*)d_in[2];
  const float* Wk = (const float*)d_in[3];
  const float* bk = (const float*)d_in[4];
  const float* Wv = (const float*)d_in[5];
  const float* bv = (const float*)d_in[6];
  const float* Wl = (const float*)d_in[7];
  const float* bl = (const float*)d_in[8];
  const float* Wo = (const float*)d_in[9];
  const float* bo = (const float*)d_in[10];

  char* ws = (char*)d_ws;
  size_t off = 0;
  auto alloc = [&](size_t bytes) { char* p = ws + off; off += bytes; return p; };

  unsigned short* xbf  = (unsigned short*)alloc((size_t)MTOT * DD * 2);      // 8 MB
  unsigned short* Wcat = (unsigned short*)alloc((size_t)4352 * DD * 2);      // 8.9 MB
  unsigned short* Qp   = (unsigned short*)alloc((size_t)MTOT * DD * 2);      // [B,H,T,64]
  unsigned short* Kp   = (unsigned short*)alloc((size_t)MTOT * DD * 2);
  unsigned short* Vtb  = (unsigned short*)alloc((size_t)MTOT * DD * 2);      // [B,H,64,T]
  float*          lamp = (float*)alloc((size_t)32 * TT * 12 * 4);            // [B,H,T,12]
  unsigned short* Y    = (unsigned short*)alloc((size_t)MTOT * DD * 2);
  (void)ws_size; (void)off; (void)in_sizes; (void)n_in; (void)out_size;

  cast_x_kernel<<<MTOT * DD / 4 / 256, 256, 0, stream>>>(x, xbf);
  transpose_all<<<dim3(136, 32), dim3(32, 8), 0, stream>>>(Wq, Wk, Wv, Wl, Wo, Wcat);

  gemm2<128, 0, 0><<<832, 256, 0, stream>>>(
      xbf, Wcat, bq, bk, bv, bl, Qp, Kp, Vtb, lamp);

  attn_fenwick2<<<512, 256, 0, stream>>>(Qp, Kp, Vtb, lamp, Y);

  gemm2<64, 1, 1><<<512, 256, 0, stream>>>(
      Y, Wcat + (size_t)3328 * 1024, bo, nullptr, nullptr, nullptr,
      (float*)d_out, nullptr, nullptr, nullptr);
}

// Round 9
// 125.300 us; speedup vs baseline: 1.1183x; 1.0454x over previous
//
#include <hip/hip_runtime.h>

// Problem constants (B=2, T=2048, D=1024, H=16, L=12, DH=64)
#define TT 2048
#define DD 1024
#define MTOT 4096   // B*T

typedef float f32x4  __attribute__((ext_vector_type(4)));
typedef float f32x16 __attribute__((ext_vector_type(16)));

__device__ __forceinline__ unsigned short f2bf(float f) {
  union { float f; unsigned u; } c; c.f = f;
  return (unsigned short)((c.u + 0x7fffu + ((c.u >> 16) & 1u)) >> 16);
}

__device__ __forceinline__ void mfma16(f32x4& d, f32x4 a, f32x4 b) {
  asm volatile("v_mfma_f32_16x16x32_bf16 %0, %1, %2, %0" : "+v"(d) : "v"(a), "v"(b));
}
__device__ __forceinline__ void mfma32(f32x16& d, f32x4 a, f32x4 b) {
  asm volatile("v_mfma_f32_32x32x16_bf16 %0, %1, %2, %0" : "+v"(d) : "v"(a), "v"(b));
}
__device__ __forceinline__ float cvtpk(float lo, float hi) {
  float r;
  asm("v_cvt_pk_bf16_f32 %0, %1, %2" : "=v"(r) : "v"(lo), "v"(hi));
  return r;
}
__device__ __forceinline__ void plswap(float& a, float& b) {
  asm volatile("v_permlane32_swap_b32 %0, %1" : "+v"(a), "+v"(b));
}
__device__ __forceinline__ void gld16(void* lds, const void* g) {
  __builtin_amdgcn_global_load_lds(
      (const __attribute__((address_space(1))) unsigned int*)g,
      (__attribute__((address_space(3))) unsigned int*)lds, 16, 0, 0);
}
__device__ __forceinline__ void mfma_fence() {
  asm volatile("s_nop 7\n\ts_nop 7\n\ts_nop 7");
}
__device__ __forceinline__ void snop1() { asm volatile("s_nop 1"); }

// ---------------- prep kernels ----------------

__global__ void cast_x_kernel(const float* __restrict__ x, unsigned short* __restrict__ xbf) {
  int i = blockIdx.x * 256 + threadIdx.x;
  float4 v = ((const float4*)x)[i];
  ushort4 o; o.x = f2bf(v.x); o.y = f2bf(v.y); o.z = f2bf(v.z); o.w = f2bf(v.w);
  ((ushort4*)xbf)[i] = o;
}

// Fused transpose: Wcat[4352][1024] bf16 = [Wq^T;Wk^T;Wv^T;Wl^T;pad;Wo^T]
__global__ void transpose_all(const float* __restrict__ Wq, const float* __restrict__ Wk,
                              const float* __restrict__ Wv, const float* __restrict__ Wl,
                              const float* __restrict__ Wo, unsigned short* __restrict__ Wcat) {
  __shared__ float tile[32][33];
  int n0 = blockIdx.x * 32, k0 = blockIdx.y * 32;
  int tx = threadIdx.x, ty = threadIdx.y;  // 32 x 8
  const float* src; int scol = 0, sN = 1024;
  if (n0 < 1024)      { src = Wq; scol = n0; }
  else if (n0 < 2048) { src = Wk; scol = n0 - 1024; }
  else if (n0 < 3072) { src = Wv; scol = n0 - 2048; }
  else if (n0 < 3264) { src = Wl; scol = n0 - 3072; sN = 192; }
  else if (n0 < 3328) { src = nullptr; }
  else                { src = Wo; scol = n0 - 3328; }
  if (src) {
#pragma unroll
    for (int i = 0; i < 4; ++i) tile[ty + i * 8][tx] = src[(k0 + ty + i * 8) * sN + scol + tx];
  }
  __syncthreads();
#pragma unroll
  for (int i = 0; i < 4; ++i)
    Wcat[(n0 + ty + i * 8) * 1024 + k0 + tx] = src ? f2bf(tile[tx][ty + i * 8]) : (unsigned short)0;
}

// ---------------- QKVL GEMM: 256x128 tile, 512 thr, proven 2-barrier loop ----
// C = A[4096,1024]*Bt[3328,1024]^T + bias, fused QKVL epilogue.
// 8 waves (4M x 2N), per-wave 64x64 out (acc[4][4], proven shape). LDS 48KB
// single-buffer -> 3 blocks/CU (24 waves). Loads/thread/step = 6 (<=8: the
// session-measured LDS-DMA outstanding limit; >8 corrupts — R5/R6/R7).
__global__ __launch_bounds__(512, 4) void gemm_qkvl512(
    const unsigned short* __restrict__ A, const unsigned short* __restrict__ Bt,
    const float* __restrict__ b0p, const float* __restrict__ b1p,
    const float* __restrict__ b2p, const float* __restrict__ b3p,
    void* __restrict__ o0p, void* __restrict__ o1p, void* __restrict__ o2p, void* __restrict__ o3p) {
  __shared__ unsigned short As[256 * 64];   // 32KB, 128B rows, 8-chunk XOR swz
  __shared__ unsigned short Bs[128 * 64];   // 16KB
  const int tid = threadIdx.x;
  const int wid = tid >> 6, lane = tid & 63, l16 = lane & 15, g = lane >> 4;
  const int wm = wid >> 1, wn = wid & 1;    // 4 m-quarters x 2 n-halves

  // 2D XCD chunking over 416 blocks = 8 XCD * (13x * 4y)
  int bx, by;
  {
    int bid = blockIdx.x;
    int xcd = bid & 7, idx = bid >> 3;
    int lx = idx % 13, ly = idx / 13;
    bx = (xcd & 1) * 13 + lx;
    by = (xcd >> 1) * 4 + ly;
  }
  const int m0 = by * 256, n0 = bx * 128;
  const int rowlane = lane >> 3;
  const int swz = (lane & 7) ^ rowlane;

  f32x4 acc[4][4] = {};

  for (int kb = 0; kb < 16; ++kb) {
    __syncthreads();
#pragma unroll
    for (int i = 0; i < 4; ++i) {            // A: 32 chunks, 4/wave
      int c = wid * 4 + i;
      int row = c * 8 + rowlane;
      gld16((char*)As + c * 1024, A + (size_t)(m0 + row) * 1024 + kb * 64 + swz * 8);
    }
#pragma unroll
    for (int i = 0; i < 2; ++i) {            // B: 16 chunks, 2/wave
      int c = wid * 2 + i;
      int row = c * 8 + rowlane;
      gld16((char*)Bs + c * 1024, Bt + (size_t)(n0 + row) * 1024 + kb * 64 + swz * 8);
    }
    __syncthreads();
#pragma unroll
    for (int kk = 0; kk < 2; ++kk) {
      f32x4 a[4], b[4];
#pragma unroll
      for (int f = 0; f < 4; ++f) {
        int ra = wm * 64 + f * 16 + l16;
        a[f] = *(const f32x4*)((const char*)As + ra * 128 + (((kk * 4 + g) ^ (ra & 7)) << 4));
        int rb = wn * 64 + f * 16 + l16;
        b[f] = *(const f32x4*)((const char*)Bs + rb * 128 + (((kk * 4 + g) ^ (rb & 7)) << 4));
      }
#pragma unroll
      for (int mf = 0; mf < 4; ++mf)
#pragma unroll
        for (int nf = 0; nf < 4; ++nf) mfma16(acc[mf][nf], a[mf], b[nf]);
    }
  }
  mfma_fence();

  // epilogue: m = m0+wm*64+mf*16+g*4+r ; n = n0+wn*64+nf*16+l16
#pragma unroll
  for (int nf = 0; nf < 4; ++nf) {
    int n = n0 + wn * 64 + nf * 16 + l16;
#pragma unroll
    for (int mf = 0; mf < 4; ++mf) {
      int m = m0 + wm * 64 + mf * 16 + g * 4;
      int bb = m >> 11, t = m & 2047;
      f32x4 v = acc[mf][nf];
      int seg = n >> 10;                     // 0=Q 1=K 2=V 3=lam (uniform per block)
      int np = n & 1023;
      if (seg <= 1) {
        float bv = seg == 0 ? b0p[np] : b1p[np];
        unsigned short* dst = (unsigned short*)(seg == 0 ? o0p : o1p) +
            ((size_t)((bb << 4) + (np >> 6)) * TT + t) * 64 + (np & 63);
#pragma unroll
        for (int r = 0; r < 4; ++r) dst[r * 64] = f2bf(v[r] + bv);
      } else if (seg == 2) {
        float bv = b2p[np];
        ushort4 pk;
        pk.x = f2bf(v[0] + bv); pk.y = f2bf(v[1] + bv);
        pk.z = f2bf(v[2] + bv); pk.w = f2bf(v[3] + bv);
        *(ushort4*)((unsigned short*)o2p +
            ((size_t)((bb << 4) + (np >> 6)) * 64 + (np & 63)) * TT + t) = pk;
      } else if (np < 192) {
        float bv = b3p[np];
        int h = np / 12, l = np - h * 12;
        float* dst = (float*)o3p + ((size_t)((bb << 4) + h) * TT + t) * 12 + l;
#pragma unroll
        for (int r = 0; r < 4; ++r) {
          float s = v[r] + bv;
          dst[r * 12] = fmaxf(s, 0.f) + log1pf(expf(-fabsf(s)));
        }
      }
    }
  }
}

// ---------------- final GEMM: 128x128 tile, 512 thr, 2-barrier ----------------
// out = Y[4096,1024]*Wo^T + bo (fp32). 8 waves (4M x 2N), per-wave 32x64
// (acc[2][4]). 4 loads/thread/step. Grid 256 = 1 block/CU exactly.
__global__ __launch_bounds__(512, 4) void gemm_outk(
    const unsigned short* __restrict__ A, const unsigned short* __restrict__ Bt,
    const float* __restrict__ bias, float* __restrict__ out) {
  __shared__ unsigned short As[128 * 64];
  __shared__ unsigned short Bs[128 * 64];
  const int tid = threadIdx.x;
  const int wid = tid >> 6, lane = tid & 63, l16 = lane & 15, g = lane >> 4;
  const int wm = wid >> 1, wn = wid & 1;    // 4 m-quarters (32 rows) x 2 n-halves

  int bx, by;
  {
    int bid = blockIdx.x;                    // 256 = 8 XCD * (8x * 4y)
    int xcd = bid & 7, idx = bid >> 3;
    bx = idx & 7;
    by = xcd * 4 + (idx >> 3);
  }
  const int m0 = by * 128, n0 = bx * 128;
  const int rowlane = lane >> 3;
  const int swz = (lane & 7) ^ rowlane;

  f32x4 acc[2][4] = {};

  for (int kb = 0; kb < 16; ++kb) {
    __syncthreads();
#pragma unroll
    for (int i = 0; i < 2; ++i) {            // A: 16 chunks, 2/wave
      int c = wid * 2 + i;
      int row = c * 8 + rowlane;
      gld16((char*)As + c * 1024, A + (size_t)(m0 + row) * 1024 + kb * 64 + swz * 8);
    }
#pragma unroll
    for (int i = 0; i < 2; ++i) {            // B: 16 chunks, 2/wave
      int c = wid * 2 + i;
      int row = c * 8 + rowlane;
      gld16((char*)Bs + c * 1024, Bt + (size_t)(n0 + row) * 1024 + kb * 64 + swz * 8);
    }
    __syncthreads();
#pragma unroll
    for (int kk = 0; kk < 2; ++kk) {
      f32x4 a[2], b[4];
#pragma unroll
      for (int f = 0; f < 2; ++f) {
        int ra = wm * 32 + f * 16 + l16;
        a[f] = *(const f32x4*)((const char*)As + ra * 128 + (((kk * 4 + g) ^ (ra & 7)) << 4));
      }
#pragma unroll
      for (int f = 0; f < 4; ++f) {
        int rb = wn * 64 + f * 16 + l16;
        b[f] = *(const f32x4*)((const char*)Bs + rb * 128 + (((kk * 4 + g) ^ (rb & 7)) << 4));
      }
#pragma unroll
      for (int mf = 0; mf < 2; ++mf)
#pragma unroll
        for (int nf = 0; nf < 4; ++nf) mfma16(acc[mf][nf], a[mf], b[nf]);
    }
  }
  mfma_fence();

#pragma unroll
  for (int nf = 0; nf < 4; ++nf) {
    int n = n0 + wn * 64 + nf * 16 + l16;
    float bv = bias[n];
#pragma unroll
    for (int mf = 0; mf < 2; ++mf) {
      int m = m0 + wm * 32 + mf * 16 + g * 4;
      f32x4 v = acc[mf][nf];
      float* dst = out + ((size_t)m << 10) + n;
#pragma unroll
      for (int r = 0; r < 4; ++r) dst[(size_t)r << 10] = v[r] + bv;
    }
  }
}

// ---------------- Fenwick-masked attention v2 (R8-proven, byte-identical) ----
__global__ __launch_bounds__(256, 2) void attn_fenwick2(
    const unsigned short* __restrict__ Qp, const unsigned short* __restrict__ Kp,
    const unsigned short* __restrict__ Vt, const float* __restrict__ lamp,
    unsigned short* __restrict__ Y) {
  __shared__ unsigned short Ks[2][64 * 128];  // [r=key&63][h*64+d], 16-chunk XOR swz
  __shared__ unsigned short Vs[2][64 * 128];  // [d][key], 16-chunk XOR swz
  __shared__ float laml[12 * 128];            // [lvl][q] -> bank = q (conflict-free)

  const int tid = threadIdx.x;
  const int w = tid >> 6, lane = tid & 63;
  const int q5 = lane & 31, hi = lane >> 5;

  // XCD-local + balanced mapping (bijective over [0,512))
  int bx = blockIdx.x;
  int lo = bx & 255;
  int bh = (lo & 7) * 4 + ((lo >> 3) & 3);
  int j0 = lo >> 5;
  int jq = (bx < 256) ? j0 : 15 - j0;

  const int qloc = w * 32 + q5;
  const int tqg = jq * 128 + qloc;

  {
    const float* src = lamp + ((size_t)bh * TT + jq * 128) * 12;
    for (int i = tid; i < 1536; i += 256) {
      int q = i / 12, l = i - q * 12;
      laml[l * 128 + q] = src[i];
    }
  }

  // Q B-frags (4 k-slices of 16): lane holds Q[tq][ks*16 + hi*8 .. +8)
  f32x4 qf[4];
  {
    const unsigned short* Qrow = Qp + ((size_t)bh * TT + tqg) * 64;
#pragma unroll
    for (int ks = 0; ks < 4; ++ks) qf[ks] = *(const f32x4*)(Qrow + ks * 16 + hi * 8);
  }

  f32x16 o0 = (f32x16)0.f, o1 = (f32x16)0.f;

  const unsigned short* Kbh = Kp + (size_t)bh * (TT * 64);
  const unsigned short* Vbh = Vt + (size_t)bh * (64 * TT);

  auto stage = [&](int kb, int buf) {
#pragma unroll
    for (int i = 0; i < 4; ++i) {
      int ch = w * 4 + i;
      int o = ch * 1024 + lane * 16;
      int r = o >> 8;                // dest row
      int cp = (o >> 4) & 15;        // swizzled chunk-in-row
      int c = cp ^ (r & 15);
      gld16((char*)&Ks[buf][0] + ch * 1024,
            Kbh + (size_t)(kb * 128 + (c >> 3) * 64 + r) * 64 + (c & 7) * 8);
      gld16((char*)&Vs[buf][0] + ch * 1024,
            Vbh + (size_t)r * TT + kb * 128 + c * 8);
    }
  };

  stage(0, 0);
  int cur = 0;

  for (int kb = 0; kb <= jq; ++kb) {
    __syncthreads();                 // drains vmcnt: buf[cur] staged; joins waves
    if (kb < jq) stage(kb + 1, cur ^ 1);
    const char* Kbase = (const char*)&Ks[cur][0];
    const char* Vbase = (const char*)&Vs[cur][0];
    const bool diag = (kb == jq);
    const int ntiles = diag ? (w + 1) : 4;

    // S^T = K * Q^T per 32-key tile: lane owns col q=q5, rows=keys
    f32x16 s[4];
#pragma unroll
    for (int t = 0; t < 4; ++t) {
      if (t >= ntiles) continue;
      s[t] = (f32x16)0.f;
      int r = (t & 1) * 32 + q5;
      int h = t >> 1;
#pragma unroll
      for (int ks = 0; ks < 4; ++ks) {
        int c = h * 8 + ks * 2 + hi;
        f32x4 kf = *(const f32x4*)(Kbase + r * 256 + ((c ^ (r & 15)) << 4));
        mfma32(s[t], kf, qf[ks]);
      }
    }
    mfma_fence();

#pragma unroll
    for (int t = 0; t < 4; ++t) {
      if (t >= ntiles) continue;
      int key64 = (kb << 1) + (t >> 1);
      float pkv[8];
      if (!diag || ((t >> 1) != (w >> 1))) {
        int lvl = 37 - __clz(((tqg + 1) >> 6) ^ key64);
        float wv = laml[lvl * 128 + qloc];
#pragma unroll
        for (int i = 0; i < 8; ++i)
          pkv[i] = cvtpk(s[t][2 * i] * wv, s[t][2 * i + 1] * wv);
      } else {
        // per-element level (+causal) — same 64-block
#pragma unroll
        for (int i = 0; i < 8; ++i) {
          float pe[2];
#pragma unroll
          for (int e = 0; e < 2; ++e) {
            int reg = 2 * i + e;
            int tig = kb * 128 + t * 32 + (reg & 3) + 8 * (reg >> 2) + 4 * hi;
            float pv = 0.f;
            if (tig <= tqg) {
              int lvl = 31 - __clz((tqg + 1) ^ tig);
              pv = s[t][reg] * laml[lvl * 128 + qloc];
            }
            pe[e] = pv;
          }
          pkv[i] = cvtpk(pe[0], pe[1]);
        }
      }
      // redistribute: pkv[0..3] = B-frag(kstep 2t), pkv[4..7] = B-frag(2t+1)
      plswap(pkv[0], pkv[2]);
      plswap(pkv[1], pkv[3]);
      plswap(pkv[4], pkv[6]);
      plswap(pkv[5], pkv[7]);
      f32x4 f0 = {pkv[0], pkv[1], pkv[2], pkv[3]};
      f32x4 f1 = {pkv[4], pkv[5], pkv[6], pkv[7]};
      snop1();
      int s0c = 4 * t + hi;          // Vs chunk = 2*kstep + hi
#pragma unroll
      for (int dg = 0; dg < 2; ++dg) {
        int row = dg * 32 + q5;
        f32x4 v0 = *(const f32x4*)(Vbase + row * 256 + ((s0c ^ (row & 15)) << 4));
        f32x4 v1 = *(const f32x4*)(Vbase + row * 256 + (((s0c + 2) ^ (row & 15)) << 4));
        if (dg) { mfma32(o1, v0, f0); mfma32(o1, v1, f1); }
        else    { mfma32(o0, v0, f0); mfma32(o0, v1, f1); }
      }
    }
    cur ^= 1;
  }
  mfma_fence();

  // store: O^T col=q (lane), rows d = dg*32 + 8*rq + 4*hi + (0..3)
  int b = bh >> 4, h = bh & 15;
  unsigned short* yrow = Y + ((size_t)(b * TT + tqg)) * DD + h * 64;
#pragma unroll
  for (int dg = 0; dg < 2; ++dg) {
    f32x16 o = dg ? o1 : o0;
#pragma unroll
    for (int rq = 0; rq < 4; ++rq) {
      ushort4 pk;
      pk.x = f2bf(o[4 * rq + 0]); pk.y = f2bf(o[4 * rq + 1]);
      pk.z = f2bf(o[4 * rq + 2]); pk.w = f2bf(o[4 * rq + 3]);
      *(ushort4*)(yrow + dg * 32 + 8 * rq + 4 * hi) = pk;
    }
  }
}

// ---------------- host ----------------

extern "C" void kernel_launch(void* const* d_in, const int* in_sizes, int n_in,
                              void* d_out, int out_size, void* d_ws, size_t ws_size,
                              hipStream_t stream) {
  const float* x  = (const float*)d_in[0];
  const float* Wq = (const float*)d_in[1];
  const float* bq = (const float*)d_in[2];
  const float* Wk = (const float*)d_in[3];
  const float* bk = (const float*)d_in[4];
  const float* Wv = (const float*)d_in[5];
  const float* bv = (const float*)d_in[6];
  const float* Wl = (const float*)d_in[7];
  const float* bl = (const float*)d_in[8];
  const float* Wo = (const float*)d_in[9];
  const float* bo = (const float*)d_in[10];

  char* ws = (char*)d_ws;
  size_t off = 0;
  auto alloc = [&](size_t bytes) { char* p = ws + off; off += bytes; return p; };

  unsigned short* xbf  = (unsigned short*)alloc((size_t)MTOT * DD * 2);      // 8 MB
  unsigned short* Wcat = (unsigned short*)alloc((size_t)4352 * DD * 2);      // 8.9 MB
  unsigned short* Qp   = (unsigned short*)alloc((size_t)MTOT * DD * 2);      // [B,H,T,64]
  unsigned short* Kp   = (unsigned short*)alloc((size_t)MTOT * DD * 2);
  unsigned short* Vtb  = (unsigned short*)alloc((size_t)MTOT * DD * 2);      // [B,H,64,T]
  float*          lamp = (float*)alloc((size_t)32 * TT * 12 * 4);            // [B,H,T,12]
  unsigned short* Y    = (unsigned short*)alloc((size_t)MTOT * DD * 2);
  (void)ws_size; (void)off; (void)in_sizes; (void)n_in; (void)out_size;

  cast_x_kernel<<<MTOT * DD / 4 / 256, 256, 0, stream>>>(x, xbf);
  transpose_all<<<dim3(136, 32), dim3(32, 8), 0, stream>>>(Wq, Wk, Wv, Wl, Wo, Wcat);

  gemm_qkvl512<<<416, 512, 0, stream>>>(
      xbf, Wcat, bq, bk, bv, bl, Qp, Kp, Vtb, lamp);

  attn_fenwick2<<<512, 256, 0, stream>>>(Qp, Kp, Vtb, lamp, Y);

  gemm_outk<<<256, 512, 0, stream>>>(
      Y, Wcat + (size_t)3328 * 1024, bo, (float*)d_out);
}

// Round 11
// 122.933 us; speedup vs baseline: 1.1398x; 1.0193x over previous
//
#include <hip/hip_runtime.h>

// Problem constants (B=2, T=2048, D=1024, H=16, L=12, DH=64)
#define TT 2048
#define DD 1024
#define MTOT 4096   // B*T

typedef float f32x4  __attribute__((ext_vector_type(4)));
typedef float f32x16 __attribute__((ext_vector_type(16)));

__device__ __forceinline__ unsigned short f2bf(float f) {
  union { float f; unsigned u; } c; c.f = f;
  return (unsigned short)((c.u + 0x7fffu + ((c.u >> 16) & 1u)) >> 16);
}

__device__ __forceinline__ void mfma16(f32x4& d, f32x4 a, f32x4 b) {
  asm volatile("v_mfma_f32_16x16x32_bf16 %0, %1, %2, %0" : "+v"(d) : "v"(a), "v"(b));
}
__device__ __forceinline__ void mfma32(f32x16& d, f32x4 a, f32x4 b) {
  asm volatile("v_mfma_f32_32x32x16_bf16 %0, %1, %2, %0" : "+v"(d) : "v"(a), "v"(b));
}
__device__ __forceinline__ float cvtpk(float lo, float hi) {
  float r;
  asm("v_cvt_pk_bf16_f32 %0, %1, %2" : "=v"(r) : "v"(lo), "v"(hi));
  return r;
}
__device__ __forceinline__ void plswap(float& a, float& b) {
  asm volatile("v_permlane32_swap_b32 %0, %1" : "+v"(a), "+v"(b));
}
__device__ __forceinline__ void gld16(void* lds, const void* g) {
  __builtin_amdgcn_global_load_lds(
      (const __attribute__((address_space(1))) unsigned int*)g,
      (__attribute__((address_space(3))) unsigned int*)lds, 16, 0, 0);
}
__device__ __forceinline__ void mfma_fence() {
  asm volatile("s_nop 7\n\ts_nop 7\n\ts_nop 7");
}
__device__ __forceinline__ void snop1() { asm volatile("s_nop 1"); }

// ---------------- fused prep: cast x (blocks 0..4095) + transpose W (rest) ----
// Wcat[4352][1024] bf16 = [Wq^T;Wk^T;Wv^T;Wl^T;pad;Wo^T]
__global__ void prep_fused(const float* __restrict__ x, unsigned short* __restrict__ xbf,
                           const float* __restrict__ Wq, const float* __restrict__ Wk,
                           const float* __restrict__ Wv, const float* __restrict__ Wl,
                           const float* __restrict__ Wo, unsigned short* __restrict__ Wcat) {
  const int bid = blockIdx.x, tid = threadIdx.x;
  if (bid < 4096) {                       // cast: one float4 per thread
    int i = bid * 256 + tid;
    float4 v = ((const float4*)x)[i];
    ushort4 o; o.x = f2bf(v.x); o.y = f2bf(v.y); o.z = f2bf(v.z); o.w = f2bf(v.w);
    ((ushort4*)xbf)[i] = o;
    return;
  }
  __shared__ float tile[32][33];
  int flat = bid - 4096;                  // 4352 blocks: 136 x-tiles * 32 k-tiles
  int n0 = (flat % 136) * 32, k0 = (flat / 136) * 32;
  int tx = tid & 31, ty = tid >> 5;       // 32 x 8
  const float* src; int scol = 0, sN = 1024;
  if (n0 < 1024)      { src = Wq; scol = n0; }
  else if (n0 < 2048) { src = Wk; scol = n0 - 1024; }
  else if (n0 < 3072) { src = Wv; scol = n0 - 2048; }
  else if (n0 < 3264) { src = Wl; scol = n0 - 3072; sN = 192; }
  else if (n0 < 3328) { src = nullptr; }
  else                { src = Wo; scol = n0 - 3328; }
  if (src) {
#pragma unroll
    for (int i = 0; i < 4; ++i) tile[ty + i * 8][tx] = src[(k0 + ty + i * 8) * sN + scol + tx];
  }
  __syncthreads();
#pragma unroll
  for (int i = 0; i < 4; ++i)
    Wcat[(n0 + ty + i * 8) * 1024 + k0 + tx] = src ? f2bf(tile[tx][ty + i * 8]) : (unsigned short)0;
}

// ---------------- QKVL GEMM (R9-proven, byte-identical): 256x128, 512 thr ----
__global__ __launch_bounds__(512, 4) void gemm_qkvl512(
    const unsigned short* __restrict__ A, const unsigned short* __restrict__ Bt,
    const float* __restrict__ b0p, const float* __restrict__ b1p,
    const float* __restrict__ b2p, const float* __restrict__ b3p,
    void* __restrict__ o0p, void* __restrict__ o1p, void* __restrict__ o2p, void* __restrict__ o3p) {
  __shared__ unsigned short As[256 * 64];   // 32KB, 128B rows, 8-chunk XOR swz
  __shared__ unsigned short Bs[128 * 64];   // 16KB
  const int tid = threadIdx.x;
  const int wid = tid >> 6, lane = tid & 63, l16 = lane & 15, g = lane >> 4;
  const int wm = wid >> 1, wn = wid & 1;    // 4 m-quarters x 2 n-halves

  // 2D XCD chunking over 416 blocks = 8 XCD * (13x * 4y)
  int bx, by;
  {
    int bid = blockIdx.x;
    int xcd = bid & 7, idx = bid >> 3;
    int lx = idx % 13, ly = idx / 13;
    bx = (xcd & 1) * 13 + lx;
    by = (xcd >> 1) * 4 + ly;
  }
  const int m0 = by * 256, n0 = bx * 128;
  const int rowlane = lane >> 3;
  const int swz = (lane & 7) ^ rowlane;

  f32x4 acc[4][4] = {};

  for (int kb = 0; kb < 16; ++kb) {
    __syncthreads();
#pragma unroll
    for (int i = 0; i < 4; ++i) {            // A: 32 chunks, 4/wave
      int c = wid * 4 + i;
      int row = c * 8 + rowlane;
      gld16((char*)As + c * 1024, A + (size_t)(m0 + row) * 1024 + kb * 64 + swz * 8);
    }
#pragma unroll
    for (int i = 0; i < 2; ++i) {            // B: 16 chunks, 2/wave
      int c = wid * 2 + i;
      int row = c * 8 + rowlane;
      gld16((char*)Bs + c * 1024, Bt + (size_t)(n0 + row) * 1024 + kb * 64 + swz * 8);
    }
    __syncthreads();
#pragma unroll
    for (int kk = 0; kk < 2; ++kk) {
      f32x4 a[4], b[4];
#pragma unroll
      for (int f = 0; f < 4; ++f) {
        int ra = wm * 64 + f * 16 + l16;
        a[f] = *(const f32x4*)((const char*)As + ra * 128 + (((kk * 4 + g) ^ (ra & 7)) << 4));
        int rb = wn * 64 + f * 16 + l16;
        b[f] = *(const f32x4*)((const char*)Bs + rb * 128 + (((kk * 4 + g) ^ (rb & 7)) << 4));
      }
#pragma unroll
      for (int mf = 0; mf < 4; ++mf)
#pragma unroll
        for (int nf = 0; nf < 4; ++nf) mfma16(acc[mf][nf], a[mf], b[nf]);
    }
  }
  mfma_fence();

  // epilogue: m = m0+wm*64+mf*16+g*4+r ; n = n0+wn*64+nf*16+l16
#pragma unroll
  for (int nf = 0; nf < 4; ++nf) {
    int n = n0 + wn * 64 + nf * 16 + l16;
#pragma unroll
    for (int mf = 0; mf < 4; ++mf) {
      int m = m0 + wm * 64 + mf * 16 + g * 4;
      int bb = m >> 11, t = m & 2047;
      f32x4 v = acc[mf][nf];
      int seg = n >> 10;                     // 0=Q 1=K 2=V 3=lam (uniform per block)
      int np = n & 1023;
      if (seg <= 1) {
        float bv = seg == 0 ? b0p[np] : b1p[np];
        unsigned short* dst = (unsigned short*)(seg == 0 ? o0p : o1p) +
            ((size_t)((bb << 4) + (np >> 6)) * TT + t) * 64 + (np & 63);
#pragma unroll
        for (int r = 0; r < 4; ++r) dst[r * 64] = f2bf(v[r] + bv);
      } else if (seg == 2) {
        float bv = b2p[np];
        ushort4 pk;
        pk.x = f2bf(v[0] + bv); pk.y = f2bf(v[1] + bv);
        pk.z = f2bf(v[2] + bv); pk.w = f2bf(v[3] + bv);
        *(ushort4*)((unsigned short*)o2p +
            ((size_t)((bb << 4) + (np >> 6)) * 64 + (np & 63)) * TT + t) = pk;
      } else if (np < 192) {
        float bv = b3p[np];
        int h = np / 12, l = np - h * 12;
        float* dst = (float*)o3p + ((size_t)((bb << 4) + h) * TT + t) * 12 + l;
#pragma unroll
        for (int r = 0; r < 4; ++r) {
          float s = v[r] + bv;
          dst[r * 12] = fmaxf(s, 0.f) + log1pf(expf(-fabsf(s)));
        }
      }
    }
  }
}

// ---------------- final GEMM: R2-proven 128^2/256thr single-buffer body -------
// out = Y[4096,1024]*Wo^T + bo (fp32). Per-wave 64x64 acc[4][4] (proven shape),
// 8 loads/thread interleaved (proven), 32KB LDS. Grid 256 = 1 block/CU,
// R9-proven XCD by-slab mapping.
__global__ __launch_bounds__(256, 2) void gemm_out128(
    const unsigned short* __restrict__ A, const unsigned short* __restrict__ Bt,
    const float* __restrict__ bias, float* __restrict__ out) {
  __shared__ unsigned short As[128 * 64];
  __shared__ unsigned short Bs[128 * 64];
  const int tid = threadIdx.x;
  const int wid = tid >> 6, lane = tid & 63, l16 = lane & 15, g = lane >> 4;
  const int wm = wid >> 1, wn = wid & 1;

  int bx, by;
  {
    int bid = blockIdx.x;                    // 256 = 8 XCD * (8x * 4y)
    int xcd = bid & 7, idx = bid >> 3;
    bx = idx & 7;
    by = xcd * 4 + (idx >> 3);
  }
  const int m0 = by * 128, n0 = bx * 128;
  const int rowlane = lane >> 3;
  const int swz = (lane & 7) ^ rowlane;

  f32x4 acc[4][4] = {};

  for (int kb = 0; kb < 16; ++kb) {
    __syncthreads();
#pragma unroll
    for (int i = 0; i < 4; ++i) {
      int c = wid * 4 + i;
      int row = c * 8 + rowlane;
      gld16((char*)As + c * 1024, A + (size_t)(m0 + row) * 1024 + kb * 64 + swz * 8);
      gld16((char*)Bs + c * 1024, Bt + (size_t)(n0 + row) * 1024 + kb * 64 + swz * 8);
    }
    __syncthreads();
#pragma unroll
    for (int kk = 0; kk < 2; ++kk) {
      f32x4 a[4], b[4];
#pragma unroll
      for (int f = 0; f < 4; ++f) {
        int ra = wm * 64 + f * 16 + l16;
        a[f] = *(const f32x4*)((const char*)As + ra * 128 + (((kk * 4 + g) ^ (ra & 7)) << 4));
        int rb = wn * 64 + f * 16 + l16;
        b[f] = *(const f32x4*)((const char*)Bs + rb * 128 + (((kk * 4 + g) ^ (rb & 7)) << 4));
      }
#pragma unroll
      for (int mf = 0; mf < 4; ++mf)
#pragma unroll
        for (int nf = 0; nf < 4; ++nf) mfma16(acc[mf][nf], a[mf], b[nf]);
    }
  }
  mfma_fence();

#pragma unroll
  for (int nf = 0; nf < 4; ++nf) {
    int n = n0 + wn * 64 + nf * 16 + l16;
    float bv = bias[n];
#pragma unroll
    for (int mf = 0; mf < 4; ++mf) {
      int m = m0 + wm * 64 + mf * 16 + g * 4;
      f32x4 v = acc[mf][nf];
      float* dst = out + ((size_t)m << 10) + n;
#pragma unroll
      for (int r = 0; r < 4; ++r) dst[(size_t)r << 10] = v[r] + bv;
    }
  }
}

// ---------------- Fenwick-masked attention v2 (R8/R9-proven, byte-identical) --
__global__ __launch_bounds__(256, 2) void attn_fenwick2(
    const unsigned short* __restrict__ Qp, const unsigned short* __restrict__ Kp,
    const unsigned short* __restrict__ Vt, const float* __restrict__ lamp,
    unsigned short* __restrict__ Y) {
  __shared__ unsigned short Ks[2][64 * 128];  // [r=key&63][h*64+d], 16-chunk XOR swz
  __shared__ unsigned short Vs[2][64 * 128];  // [d][key], 16-chunk XOR swz
  __shared__ float laml[12 * 128];            // [lvl][q] -> bank = q (conflict-free)

  const int tid = threadIdx.x;
  const int w = tid >> 6, lane = tid & 63;
  const int q5 = lane & 31, hi = lane >> 5;

  // XCD-local + balanced mapping (bijective over [0,512))
  int bx = blockIdx.x;
  int lo = bx & 255;
  int bh = (lo & 7) * 4 + ((lo >> 3) & 3);
  int j0 = lo >> 5;
  int jq = (bx < 256) ? j0 : 15 - j0;

  const int qloc = w * 32 + q5;
  const int tqg = jq * 128 + qloc;

  {
    const float* src = lamp + ((size_t)bh * TT + jq * 128) * 12;
    for (int i = tid; i < 1536; i += 256) {
      int q = i / 12, l = i - q * 12;
      laml[l * 128 + q] = src[i];
    }
  }

  // Q B-frags (4 k-slices of 16): lane holds Q[tq][ks*16 + hi*8 .. +8)
  f32x4 qf[4];
  {
    const unsigned short* Qrow = Qp + ((size_t)bh * TT + tqg) * 64;
#pragma unroll
    for (int ks = 0; ks < 4; ++ks) qf[ks] = *(const f32x4*)(Qrow + ks * 16 + hi * 8);
  }

  f32x16 o0 = (f32x16)0.f, o1 = (f32x16)0.f;

  const unsigned short* Kbh = Kp + (size_t)bh * (TT * 64);
  const unsigned short* Vbh = Vt + (size_t)bh * (64 * TT);

  auto stage = [&](int kb, int buf) {
#pragma unroll
    for (int i = 0; i < 4; ++i) {
      int ch = w * 4 + i;
      int o = ch * 1024 + lane * 16;
      int r = o >> 8;                // dest row
      int cp = (o >> 4) & 15;        // swizzled chunk-in-row
      int c = cp ^ (r & 15);
      gld16((char*)&Ks[buf][0] + ch * 1024,
            Kbh + (size_t)(kb * 128 + (c >> 3) * 64 + r) * 64 + (c & 7) * 8);
      gld16((char*)&Vs[buf][0] + ch * 1024,
            Vbh + (size_t)r * TT + kb * 128 + c * 8);
    }
  };

  stage(0, 0);
  int cur = 0;

  for (int kb = 0; kb <= jq; ++kb) {
    __syncthreads();                 // drains vmcnt: buf[cur] staged; joins waves
    if (kb < jq) stage(kb + 1, cur ^ 1);
    const char* Kbase = (const char*)&Ks[cur][0];
    const char* Vbase = (const char*)&Vs[cur][0];
    const bool diag = (kb == jq);
    const int ntiles = diag ? (w + 1) : 4;

    // S^T = K * Q^T per 32-key tile: lane owns col q=q5, rows=keys
    f32x16 s[4];
#pragma unroll
    for (int t = 0; t < 4; ++t) {
      if (t >= ntiles) continue;
      s[t] = (f32x16)0.f;
      int r = (t & 1) * 32 + q5;
      int h = t >> 1;
#pragma unroll
      for (int ks = 0; ks < 4; ++ks) {
        int c = h * 8 + ks * 2 + hi;
        f32x4 kf = *(const f32x4*)(Kbase + r * 256 + ((c ^ (r & 15)) << 4));
        mfma32(s[t], kf, qf[ks]);
      }
    }
    mfma_fence();

#pragma unroll
    for (int t = 0; t < 4; ++t) {
      if (t >= ntiles) continue;
      int key64 = (kb << 1) + (t >> 1);
      float pkv[8];
      if (!diag || ((t >> 1) != (w >> 1))) {
        int lvl = 37 - __clz(((tqg + 1) >> 6) ^ key64);
        float wv = laml[lvl * 128 + qloc];
#pragma unroll
        for (int i = 0; i < 8; ++i)
          pkv[i] = cvtpk(s[t][2 * i] * wv, s[t][2 * i + 1] * wv);
      } else {
        // per-element level (+causal) — same 64-block
#pragma unroll
        for (int i = 0; i < 8; ++i) {
          float pe[2];
#pragma unroll
          for (int e = 0; e < 2; ++e) {
            int reg = 2 * i + e;
            int tig = kb * 128 + t * 32 + (reg & 3) + 8 * (reg >> 2) + 4 * hi;
            float pv = 0.f;
            if (tig <= tqg) {
              int lvl = 31 - __clz((tqg + 1) ^ tig);
              pv = s[t][reg] * laml[lvl * 128 + qloc];
            }
            pe[e] = pv;
          }
          pkv[i] = cvtpk(pe[0], pe[1]);
        }
      }
      // redistribute: pkv[0..3] = B-frag(kstep 2t), pkv[4..7] = B-frag(2t+1)
      plswap(pkv[0], pkv[2]);
      plswap(pkv[1], pkv[3]);
      plswap(pkv[4], pkv[6]);
      plswap(pkv[5], pkv[7]);
      f32x4 f0 = {pkv[0], pkv[1], pkv[2], pkv[3]};
      f32x4 f1 = {pkv[4], pkv[5], pkv[6], pkv[7]};
      snop1();
      int s0c = 4 * t + hi;          // Vs chunk = 2*kstep + hi
#pragma unroll
      for (int dg = 0; dg < 2; ++dg) {
        int row = dg * 32 + q5;
        f32x4 v0 = *(const f32x4*)(Vbase + row * 256 + ((s0c ^ (row & 15)) << 4));
        f32x4 v1 = *(const f32x4*)(Vbase + row * 256 + (((s0c + 2) ^ (row & 15)) << 4));
        if (dg) { mfma32(o1, v0, f0); mfma32(o1, v1, f1); }
        else    { mfma32(o0, v0, f0); mfma32(o0, v1, f1); }
      }
    }
    cur ^= 1;
  }
  mfma_fence();

  // store: O^T col=q (lane), rows d = dg*32 + 8*rq + 4*hi + (0..3)
  int b = bh >> 4, h = bh & 15;
  unsigned short* yrow = Y + ((size_t)(b * TT + tqg)) * DD + h * 64;
#pragma unroll
  for (int dg = 0; dg < 2; ++dg) {
    f32x16 o = dg ? o1 : o0;
#pragma unroll
    for (int rq = 0; rq < 4; ++rq) {
      ushort4 pk;
      pk.x = f2bf(o[4 * rq + 0]); pk.y = f2bf(o[4 * rq + 1]);
      pk.z = f2bf(o[4 * rq + 2]); pk.w = f2bf(o[4 * rq + 3]);
      *(ushort4*)(yrow + dg * 32 + 8 * rq + 4 * hi) = pk;
    }
  }
}

// ---------------- host ----------------

extern "C" void kernel_launch(void* const* d_in, const int* in_sizes, int n_in,
                              void* d_out, int out_size, void* d_ws, size_t ws_size,
                              hipStream_t stream) {
  const float* x  = (const float*)d_in[0];
  const float* Wq = (const float*)d_in[1];
  const float* bq = (const float*)d_in[2];
  const float* Wk = (const float*)d_in[3];
  const float* bk = (const float*)d_in[4];
  const float* Wv = (const float*)d_in[5];
  const float* bv = (const float*)d_in[6];
  const float* Wl = (const float*)d_in[7];
  const float* bl = (const float*)d_in[8];
  const float* Wo = (const float*)d_in[9];
  const float* bo = (const float*)d_in[10];

  char* ws = (char*)d_ws;
  size_t off = 0;
  auto alloc = [&](size_t bytes) { char* p = ws + off; off += bytes; return p; };

  unsigned short* xbf  = (unsigned short*)alloc((size_t)MTOT * DD * 2);      // 8 MB
  unsigned short* Wcat = (unsigned short*)alloc((size_t)4352 * DD * 2);      // 8.9 MB
  unsigned short* Qp   = (unsigned short*)alloc((size_t)MTOT * DD * 2);      // [B,H,T,64]
  unsigned short* Kp   = (unsigned short*)alloc((size_t)MTOT * DD * 2);
  unsigned short* Vtb  = (unsigned short*)alloc((size_t)MTOT * DD * 2);      // [B,H,64,T]
  float*          lamp = (float*)alloc((size_t)32 * TT * 12 * 4);            // [B,H,T,12]
  unsigned short* Y    = (unsigned short*)alloc((size_t)MTOT * DD * 2);
  (void)ws_size; (void)off; (void)in_sizes; (void)n_in; (void)out_size;

  prep_fused<<<4096 + 4352, 256, 0, stream>>>(x, xbf, Wq, Wk, Wv, Wl, Wo, Wcat);

  gemm_qkvl512<<<416, 512, 0, stream>>>(
      xbf, Wcat, bq, bk, bv, bl, Qp, Kp, Vtb, lamp);

  attn_fenwick2<<<512, 256, 0, stream>>>(Qp, Kp, Vtb, lamp, Y);

  gemm_out128<<<256, 256, 0, stream>>>(
      Y, Wcat + (size_t)3328 * 1024, bo, (float*)d_out);
}